// Round 6
// baseline (380.437 us; speedup 1.0000x reference)
//
#include <hip/hip_runtime.h>

#define NB 4
#define CIN 64
#define COUT 64
#define H 128
#define W 128
#define H2 256
#define W2 256
#define HS 24             // halo LDS row stride (dwords)
#define ZS 36             // zbuf row stride (ushorts) = 72B -> 16-bank spread

// ws layout (float units)
#define WS_W    0         // bf16 weights ushort[32][64][32] = 32768 floats
#define WS_P1   32768     // per-tile partial sums  [4*64][256]
#define WS_P2   98304     // per-tile partial sumsq [4*64][256]
#define WS_MU   163840
#define WS_RSTD 164096

// ---------------------------------------------------------------------------
// Compile-time DISCO basis (replicates the numpy double-precision computation)
// ---------------------------------------------------------------------------
constexpr double csqrt(double x) {
    double g = x > 1.0 ? x : 1.0;
    for (int i = 0; i < 64; ++i) g = 0.5 * (g + x / g);
    return g;
}
constexpr double catan_pos(double x) {
    double f = 1.0;
    for (int i = 0; i < 6; ++i) { x = x / (1.0 + csqrt(1.0 + x * x)); f *= 2.0; }
    double x2 = x * x, s = 0.0, term = x;
    for (int n = 0; n < 10; ++n) { s += term / (2 * n + 1) * ((n & 1) ? -1.0 : 1.0); term *= x2; }
    return f * s;
}
constexpr double catan2c(double y, double x) {
    const double PI = 3.141592653589793;
    if (x == 0.0 && y == 0.0) return 0.0;
    double ax = x < 0 ? -x : x, ay = y < 0 ? -y : y;
    double a = (ax >= ay) ? catan_pos(ay / ax) : (PI / 2.0 - catan_pos(ax / ay));
    if (x < 0) a = PI - a;
    return (y < 0) ? -a : a;
}

struct PsiTab { double v[81][9]; };
constexpr PsiTab compute_psi() {
    PsiTab P{};
    const double hy = 1.0 / 256.0;
    const double rcut = 0.015;
    const double dr = 0.0075;
    const double PI = 3.141592653589793;
    const double TWO_PI = 6.283185307179586;
    const double dphi = PI / 2.0;
    for (int ky = 0; ky < 9; ++ky)
        for (int kx = 0; kx < 9; ++kx) {
            double dy = (double)(ky - 4) * hy;
            double dx = (double)(kx - 4) * hy;
            double r = csqrt(dy * dy + dx * dx);
            double phi = catan2c(dy, dx);
            if (phi < 0.0) phi += TWO_PI;
            for (int k = 0; k < 9; ++k) {
                int ir = (k == 0) ? 0 : ((k - 1) / 4 + 1);
                double ctr = ir * dr;
                double ad = r > ctr ? r - ctr : ctr - r;
                double rv = (ad <= dr && r <= rcut) ? 1.0 - ad / dr : 0.0;
                double val;
                if (k == 0) val = rv;
                else {
                    int ip = (k - 1) % 4;
                    double da = phi - ip * dphi; if (da < 0) da = -da;
                    double d2 = TWO_PI - da; if (d2 < da) da = d2;
                    double pv = (da <= dphi) ? 1.0 - da / dphi : 0.0;
                    val = rv * pv;
                }
                P.v[ky * 9 + kx][k] = val * (hy * hy);
            }
        }
    return P;
}

struct TapTab {
    int nt;
    int off[48];          // dy*HS + dx (dword offset from thread base)
    float val[48][9];
    bool nz[48][9];
};
constexpr TapTab make_taps() {
    TapTab T{};
    PsiTab P = compute_psi();
    for (int ky = 0; ky < 9; ++ky)
        for (int kx = 0; kx < 9; ++kx) {
            int t = ky * 9 + kx;
            bool any = false;
            for (int k = 0; k < 9; ++k) if (P.v[t][k] != 0.0) any = true;
            if (!any) continue;
            int dy = ky - 4, dx = kx - 4;    // support guarantees |dy|,|dx| <= 3
            T.off[T.nt] = dy * HS + dx;
            for (int k = 0; k < 9; ++k) {
                T.val[T.nt][k] = (float)P.v[t][k];
                T.nz[T.nt][k] = (P.v[t][k] != 0.0);
            }
            T.nt++;
        }
    return T;
}
constexpr TapTab TT = make_taps();
constexpr int NT = TT.nt;
static_assert(NT > 0 && NT <= 48, "tap table overflow");

using f32x2  = __attribute__((ext_vector_type(2))) float;
using f32x4  = __attribute__((ext_vector_type(4))) float;
using bf16x8 = __attribute__((ext_vector_type(8))) short;

__device__ __forceinline__ unsigned short f2bf_rne(float f) {
    unsigned u = __float_as_uint(f);
    unsigned r = (u + 0x7fff + ((u >> 16) & 1)) >> 16;
    return (unsigned short)r;
}
// RTZ pack of two floats to one u32 of 2 bf16 (bias cancels in InstanceNorm)
__device__ __forceinline__ unsigned pkrtz(float a, float b) {
    return (__float_as_uint(a) >> 16) | (__float_as_uint(b) & 0xffff0000u);
}

// ---------------------------------------------------------------------------
// Setup: pre-transpose weights to bf16 wsW[g][o][32]  (kk = ch*16 + k, pads 0)
// ---------------------------------------------------------------------------
__global__ void setup_w(const float* __restrict__ wgt, float* __restrict__ ws) {
    unsigned short* wsW = (unsigned short*)(ws + WS_W);
    const int g = blockIdx.x;          // channel pair 0..31
    const int t = threadIdx.x;         // 256
    const int o = t >> 2;
    const int k0 = (t & 3) * 8;
#pragma unroll
    for (int j = 0; j < 8; ++j) {
        int kk = k0 + j;
        int ch = kk >> 4, k = kk & 15;
        float v = (k < 9) ? wgt[((size_t)o * CIN + 2 * g + ch) * 9 + k] : 0.f;
        wsW[g * 2048 + o * 32 + kk] = f2bf_rne(v);
    }
}

// ---------------------------------------------------------------------------
// Fused upsample + DISCO conv. Block = 16x16 px tile (256 px), 4 waves.
// Halo CHANNEL-PAIRED bf16x2 dwords; zbuf AND halo double-buffered -> a
// single barrier per channel pair. zbuf rows 72B (16-bank spread, b64 ops).
// ---------------------------------------------------------------------------
__global__ __launch_bounds__(256, 3) void conv_kernel(const float* __restrict__ img,
                                                      float* __restrict__ out,
                                                      float* __restrict__ ws) {
    __shared__ unsigned short zbuf[2][256][ZS];  // [buf][px][kk] bf16, pads zero
    __shared__ unsigned halo[2][22 * HS];        // [buf][hy*HS+hx] ch-paired bf16x2
    __shared__ float red1[4][64], red2[4][64];

    const int tid  = threadIdx.x;
    const int bid  = blockIdx.x;
    const int n    = bid >> 8;
    const int tile = bid & 255;
    const int ty0  = (tile >> 4) << 4;
    const int tx0  = (tile & 15) << 4;

    const int r = tid >> 4, c = tid & 15;
    const int hbase = (r + 3) * HS + (c + 3);
    const int wv  = tid >> 6;
    const int l   = tid & 63;
    const int a16 = l & 15;
    const int kseg = (l >> 4) * 8;

    const unsigned short* wsW = (const unsigned short*)(ws + WS_W);

    // zero both zbuf buffers once (pads stay zero forever)
    {
        uint4* zr = (uint4*)&zbuf[0][0][0];
#pragma unroll
        for (int j = 0; j < 9; ++j) zr[tid + j * 256] = make_uint4(0, 0, 0, 0);
    }

    const float cs = (float)(127.0 / 255.0);

    // immediate staging: load -> lerp -> bf16-pair write (TLP hides latency)
    auto stage = [&](int g, int q) {
        const float* im0 = img + ((size_t)n * CIN + 2 * g) * (H * W);
        const float* im1 = im0 + H * W;
#pragma unroll
        for (int j = 0; j < 2; ++j) {
            int e = tid + j * 256;
            if (e < 484) {
                int hy = e / 22, hx = e - hy * 22;
                int uy = ty0 - 3 + hy, ux = tx0 - 3 + hx;
                bool zf = ((unsigned)uy >= 256u) || ((unsigned)ux >= 256u);
                float syf = (float)uy * cs;
                float sxf = (float)ux * cs;
                int y0 = (int)syf; y0 = min(max(y0, 0), 127);
                int x0 = (int)sxf; x0 = min(max(x0, 0), 127);
                int y1 = min(y0 + 1, 127), x1 = min(x0 + 1, 127);
                float fy = syf - (float)y0;
                float fx = sxf - (float)x0;
                int b00 = y0 * W + x0, b01 = y0 * W + x1;
                int b10 = y1 * W + x0, b11 = y1 * W + x1;
                float p00 = im0[b00], p01 = im0[b01], p10 = im0[b10], p11 = im0[b11];
                float q00 = im1[b00], q01 = im1[b01], q10 = im1[b10], q11 = im1[b11];
                float t0 = p00 + fy * (p10 - p00);
                float t1 = p01 + fy * (p11 - p01);
                float v0 = t0 + fx * (t1 - t0);
                float u0 = q00 + fy * (q10 - q00);
                float u1 = q01 + fy * (q11 - q01);
                float v1 = u0 + fx * (u1 - u0);
                if (zf) { v0 = 0.f; v1 = 0.f; }
                halo[q][hy * HS + hx] = (unsigned)f2bf_rne(v0) | ((unsigned)f2bf_rne(v1) << 16);
            }
        }
    };

    auto zphase = [&](int q, int p) {
        // pre-offset so all tap offsets are non-negative immediates (ds_read2)
        const unsigned* hb = &halo[q][hbase - 75];
        f32x2 z[9];
#pragma unroll
        for (int k = 0; k < 9; ++k) z[k] = (f32x2){0.f, 0.f};
#pragma unroll
        for (int t = 0; t < NT; ++t) {
            unsigned d = hb[75 + TT.off[t]];
            float lo = __uint_as_float(d << 16);
            float hi = __uint_as_float(d & 0xffff0000u);
#pragma unroll
            for (int k = 0; k < 9; ++k)
                if (TT.nz[t][k]) {
                    z[k].x = fmaf(TT.val[t][k], lo, z[k].x);
                    z[k].y = fmaf(TT.val[t][k], hi, z[k].y);
                }
        }
        unsigned short* zr = &zbuf[p][tid][0];
        ((uint2*)zr)[0] = make_uint2(pkrtz(z[0].x, z[1].x), pkrtz(z[2].x, z[3].x));
        ((uint2*)zr)[1] = make_uint2(pkrtz(z[4].x, z[5].x), pkrtz(z[6].x, z[7].x));
        zr[8] = (unsigned short)(__float_as_uint(z[8].x) >> 16);
        ((uint2*)(zr + 16))[0] = make_uint2(pkrtz(z[0].y, z[1].y), pkrtz(z[2].y, z[3].y));
        ((uint2*)(zr + 16))[1] = make_uint2(pkrtz(z[4].y, z[5].y), pkrtz(z[6].y, z[7].y));
        zr[24] = (unsigned short)(__float_as_uint(z[8].y) >> 16);
    };

    f32x4 acc[4][4];
#pragma unroll
    for (int m = 0; m < 4; ++m)
#pragma unroll
        for (int t = 0; t < 4; ++t) acc[m][t] = (f32x4){0.f, 0.f, 0.f, 0.f};

    stage(0, 0);
    int p = 0;   // zbuf buffer toggles every iter; halo buffer = p as well

#pragma unroll 1
    for (int g = 0; g < 32; ++g) {
        if (g > 0) {
            // barrier of previous iteration covers: halo[p] staged, zbuf[p^1] consumed
        }
        if (g < 31) stage(g + 1, p ^ 1);   // overlaps zphase in other waves
        zphase(p, p);
        __syncthreads();                    // zbuf[p] ready; halo[p^1] ready

        // A-fragments from global (L2-hot) + B-fragments from zbuf[p]
        bf16x8 af[4];
        {
            const unsigned short* wp = wsW + g * 2048 + a16 * 32 + kseg;
#pragma unroll
            for (int m = 0; m < 4; ++m)
                af[m] = *(const bf16x8*)(wp + m * 512);
        }
        union { uint2 q2[2]; bf16x8 v; } bfr[4];
#pragma unroll
        for (int t = 0; t < 4; ++t) {
            const unsigned short* zp = &zbuf[p][wv * 64 + t * 16 + a16][kseg];
            bfr[t].q2[0] = *(const uint2*)zp;
            bfr[t].q2[1] = *(const uint2*)(zp + 4);
        }
#pragma unroll
        for (int m = 0; m < 4; ++m)
#pragma unroll
            for (int t = 0; t < 4; ++t)
                acc[m][t] = __builtin_amdgcn_mfma_f32_16x16x32_bf16(af[m], bfr[t].v, acc[m][t], 0, 0, 0);
        p ^= 1;
    }

    // ---- epilogue: instance-norm partials + store y ----
#pragma unroll
    for (int m = 0; m < 4; ++m) {
#pragma unroll
        for (int r4 = 0; r4 < 4; ++r4) {
            float s = 0.f, q = 0.f;
#pragma unroll
            for (int t = 0; t < 4; ++t) {
                float v = acc[m][t][r4];
                s += v; q = fmaf(v, v, q);
            }
#pragma unroll
            for (int msk = 1; msk < 16; msk <<= 1) {
                s += __shfl_xor(s, msk);
                q += __shfl_xor(q, msk);
            }
            if (a16 == 0) {
                int o = m * 16 + (l >> 4) * 4 + r4;
                red1[wv][o] = s;
                red2[wv][o] = q;
            }
        }
    }

    const size_t nbase = (size_t)n * COUT * (H2 * W2);
#pragma unroll
    for (int m = 0; m < 4; ++m)
#pragma unroll
        for (int t = 0; t < 4; ++t) {
            int Y = ty0 + wv * 4 + t;
            int X = tx0 + a16;
#pragma unroll
            for (int r4 = 0; r4 < 4; ++r4) {
                int o = m * 16 + (l >> 4) * 4 + r4;
                out[nbase + (size_t)o * (H2 * W2) + Y * W2 + X] = acc[m][t][r4];
            }
        }
    __syncthreads();
    if (tid < 64) {
        float S1 = red1[0][tid] + red1[1][tid] + red1[2][tid] + red1[3][tid];
        float S2 = red2[0][tid] + red2[1][tid] + red2[2][tid] + red2[3][tid];
        ws[WS_P1 + (n * COUT + tid) * 256 + tile] = S1;
        ws[WS_P2 + (n * COUT + tid) * 256 + tile] = S2;
    }
}

// ---------------------------------------------------------------------------
// Stats: reduce 256 tile-partials per (n,c)
// ---------------------------------------------------------------------------
__global__ void stats_kernel(float* __restrict__ ws) {
    const int co  = blockIdx.x;
    const int tid = threadIdx.x;   // 256
    float s1 = ws[WS_P1 + co * 256 + tid];
    float s2 = ws[WS_P2 + co * 256 + tid];
#pragma unroll
    for (int m = 1; m < 64; m <<= 1) { s1 += __shfl_xor(s1, m); s2 += __shfl_xor(s2, m); }
    __shared__ float r1[4], r2[4];
    if ((tid & 63) == 0) { r1[tid >> 6] = s1; r2[tid >> 6] = s2; }
    __syncthreads();
    if (tid == 0) {
        float S1 = r1[0] + r1[1] + r1[2] + r1[3];
        float S2 = r2[0] + r2[1] + r2[2] + r2[3];
        const float inv = 1.f / 65536.f;
        float mu  = S1 * inv;
        float var = S2 * inv - mu * mu;
        ws[WS_MU + co]   = mu;
        ws[WS_RSTD + co] = 1.f / sqrtf(var + 1e-5f);
    }
}

// ---------------------------------------------------------------------------
// Normalize + LeakyReLU(0.2), in place on d_out
// ---------------------------------------------------------------------------
__global__ void norm_kernel(float* __restrict__ out, const float* __restrict__ ws) {
    const int total = NB * COUT * H2 * W2 / 4;
    for (int idx = blockIdx.x * blockDim.x + threadIdx.x; idx < total;
         idx += gridDim.x * blockDim.x) {
        int co = idx >> 14;
        float mu = ws[WS_MU + co];
        float rs = ws[WS_RSTD + co];
        float4 v = ((float4*)out)[idx];
        float* p = (float*)&v;
#pragma unroll
        for (int j = 0; j < 4; ++j) {
            float t = (p[j] - mu) * rs;
            p[j] = (t >= 0.f) ? t : 0.2f * t;
        }
        ((float4*)out)[idx] = v;
    }
}

extern "C" void kernel_launch(void* const* d_in, const int* in_sizes, int n_in,
                              void* d_out, int out_size, void* d_ws, size_t ws_size,
                              hipStream_t stream) {
    const float* img = (const float*)d_in[0];
    const float* wgt = (const float*)d_in[1];
    float* out = (float*)d_out;
    float* ws  = (float*)d_ws;

    setup_w<<<32, 256, 0, stream>>>(wgt, ws);
    conv_kernel<<<NB * 256, 256, 0, stream>>>(img, out, ws);
    stats_kernel<<<256, 256, 0, stream>>>(ws);
    norm_kernel<<<2048, 256, 0, stream>>>(out, ws);
}

// Round 7
// 163.284 us; speedup vs baseline: 2.3299x; 2.3299x over previous
//
#include <hip/hip_runtime.h>

#define NB 4
#define CIN 64
#define COUT 64
#define H 128
#define W 128
#define H2 256
#define W2 256
#define HSX 23            // halo row stride (f32x2 units)
#define ZS 40             // zbuf row stride (ushorts) = 80B

// ws layout (float units)
#define WS_W    0         // bf16 weights ushort[32][64][32] = 32768 floats
#define WS_P1   32768     // per-tile partial sums  [4*64][256]
#define WS_P2   98304     // per-tile partial sumsq [4*64][256]
#define WS_MU   163840
#define WS_RSTD 164096

// ---------------------------------------------------------------------------
// Compile-time DISCO basis (replicates the numpy double-precision computation)
// ---------------------------------------------------------------------------
constexpr double csqrt(double x) {
    double g = x > 1.0 ? x : 1.0;
    for (int i = 0; i < 64; ++i) g = 0.5 * (g + x / g);
    return g;
}
constexpr double catan_pos(double x) {
    double f = 1.0;
    for (int i = 0; i < 6; ++i) { x = x / (1.0 + csqrt(1.0 + x * x)); f *= 2.0; }
    double x2 = x * x, s = 0.0, term = x;
    for (int n = 0; n < 10; ++n) { s += term / (2 * n + 1) * ((n & 1) ? -1.0 : 1.0); term *= x2; }
    return f * s;
}
constexpr double catan2c(double y, double x) {
    const double PI = 3.141592653589793;
    if (x == 0.0 && y == 0.0) return 0.0;
    double ax = x < 0 ? -x : x, ay = y < 0 ? -y : y;
    double a = (ax >= ay) ? catan_pos(ay / ax) : (PI / 2.0 - catan_pos(ax / ay));
    if (x < 0) a = PI - a;
    return (y < 0) ? -a : a;
}

struct PsiTab { double v[81][9]; };
constexpr PsiTab compute_psi() {
    PsiTab P{};
    const double hy = 1.0 / 256.0;
    const double rcut = 0.015;
    const double dr = 0.0075;
    const double PI = 3.141592653589793;
    const double TWO_PI = 6.283185307179586;
    const double dphi = PI / 2.0;
    for (int ky = 0; ky < 9; ++ky)
        for (int kx = 0; kx < 9; ++kx) {
            double dy = (double)(ky - 4) * hy;
            double dx = (double)(kx - 4) * hy;
            double r = csqrt(dy * dy + dx * dx);
            double phi = catan2c(dy, dx);
            if (phi < 0.0) phi += TWO_PI;
            for (int k = 0; k < 9; ++k) {
                int ir = (k == 0) ? 0 : ((k - 1) / 4 + 1);
                double ctr = ir * dr;
                double ad = r > ctr ? r - ctr : ctr - r;
                double rv = (ad <= dr && r <= rcut) ? 1.0 - ad / dr : 0.0;
                double val;
                if (k == 0) val = rv;
                else {
                    int ip = (k - 1) % 4;
                    double da = phi - ip * dphi; if (da < 0) da = -da;
                    double d2 = TWO_PI - da; if (d2 < da) da = d2;
                    double pv = (da <= dphi) ? 1.0 - da / dphi : 0.0;
                    val = rv * pv;
                }
                P.v[ky * 9 + kx][k] = val * (hy * hy);
            }
        }
    return P;
}

struct TapTab {
    int nt;
    int off[48];          // dy*HSX + dx (f32x2 offset from thread base)
    float val[48][9];
    bool nz[48][9];
};
constexpr TapTab make_taps() {
    TapTab T{};
    PsiTab P = compute_psi();
    for (int ky = 0; ky < 9; ++ky)
        for (int kx = 0; kx < 9; ++kx) {
            int t = ky * 9 + kx;
            bool any = false;
            for (int k = 0; k < 9; ++k) if (P.v[t][k] != 0.0) any = true;
            if (!any) continue;
            int dy = ky - 4, dx = kx - 4;    // support guarantees |dy|,|dx| <= 3
            T.off[T.nt] = dy * HSX + dx;
            for (int k = 0; k < 9; ++k) {
                T.val[T.nt][k] = (float)P.v[t][k];
                T.nz[T.nt][k] = (P.v[t][k] != 0.0);
            }
            T.nt++;
        }
    return T;
}
constexpr TapTab TT = make_taps();
constexpr int NT = TT.nt;
static_assert(NT > 0 && NT <= 48, "tap table overflow");

using f32x2  = __attribute__((ext_vector_type(2))) float;
using f32x4  = __attribute__((ext_vector_type(4))) float;
using bf16x8 = __attribute__((ext_vector_type(8))) short;

__device__ __forceinline__ unsigned short f2bf_rne(float f) {
    unsigned u = __float_as_uint(f);
    unsigned r = (u + 0x7fff + ((u >> 16) & 1)) >> 16;
    return (unsigned short)r;
}
// RTZ pack of two floats to one u32 of 2 bf16 (bias cancels in InstanceNorm)
__device__ __forceinline__ unsigned pkrtz(float a, float b) {
    return (__float_as_uint(a) >> 16) | (__float_as_uint(b) & 0xffff0000u);
}

// ---------------------------------------------------------------------------
// Setup: pre-transpose weights to bf16 wsW[g][o][32]  (kk = ch*16 + k, pads 0)
// ---------------------------------------------------------------------------
__global__ void setup_w(const float* __restrict__ wgt, float* __restrict__ ws) {
    unsigned short* wsW = (unsigned short*)(ws + WS_W);
    const int g = blockIdx.x;          // channel pair 0..31
    const int t = threadIdx.x;         // 256
    const int o = t >> 2;
    const int k0 = (t & 3) * 8;
#pragma unroll
    for (int j = 0; j < 8; ++j) {
        int kk = k0 + j;
        int ch = kk >> 4, k = kk & 15;
        float v = (k < 9) ? wgt[((size_t)o * CIN + 2 * g + ch) * 9 + k] : 0.f;
        wsW[g * 2048 + o * 32 + kk] = f2bf_rne(v);
    }
}

// ---------------------------------------------------------------------------
// Fused upsample + DISCO conv. Block = 16x16 px tile (256 px), 4 waves.
// Per channel pair: coarse 14x14 patch (ch-paired f32x2) staged to LDS via a
// 2-register T14 pipeline; fine 22x22 halo built FROM LDS (4x ds_read_b64 +
// pk-lerp); z via compile-time taps (ds_read_b64, v_pk_fma_f32); RTZ bf16
// pack; MFMA 16x16x32 over K = 2ch x 16 (pads zero). 2 barriers/pair.
// ---------------------------------------------------------------------------
__global__ __launch_bounds__(256, 2) void conv_kernel(const float* __restrict__ img,
                                                      float* __restrict__ out,
                                                      float* __restrict__ ws) {
    __shared__ unsigned short zbuf[256][ZS];   // [px][kk] bf16, pads zero
    __shared__ f32x2 halo[2][22 * HSX];        // [buf][hy*HSX+hx] {ch0,ch1} f32
    __shared__ f32x2 coarse[2][14 * 15];       // [buf][cy*15+cx] {ch0,ch1} f32
    __shared__ float red1[4][64], red2[4][64];

    const int tid  = threadIdx.x;
    const int bid  = blockIdx.x;
    const int n    = bid >> 8;
    const int tile = bid & 255;
    const int ty0  = (tile >> 4) << 4;
    const int tx0  = (tile & 15) << 4;

    const int r = tid >> 4, c = tid & 15;
    const int hbase = (r + 3) * HSX + (c + 3);
    const int wv  = tid >> 6;
    const int l   = tid & 63;
    const int a16 = l & 15;
    const int kseg = (l >> 4) * 8;

    const unsigned short* wsW = (const unsigned short*)(ws + WS_W);

    // zero zbuf once (pads stay zero forever)
    {
        uint4* zr = (uint4*)&zbuf[0][0];
#pragma unroll
        for (int j = 0; j < 5; ++j) zr[tid + j * 256] = make_uint4(0, 0, 0, 0);
    }

    const float cs = 0.49803922f;   // 127/255

    // ---- block-constant coarse patch base ----
    int cy0 = (int)floorf((float)(ty0 - 3) * cs); cy0 = min(max(cy0, 0), 114);
    int cx0 = (int)floorf((float)(tx0 - 3) * cs); cx0 = min(max(cx0, 0), 114);

    // ---- coarse loader invariants (1 elem/thread, 196 used) ----
    const bool cok = tid < 196;
    const int ci = tid / 14, cj = tid - ci * 14;
    const int cgoff = (cy0 + ci) * W + (cx0 + cj);
    const int cwidx = ci * 15 + cj;
    float cv0 = 0.f, cv1 = 0.f;

    auto cload = [&](int g) {
        if (cok) {
            const float* b = img + ((size_t)n * CIN + 2 * g) * (H * W) + cgoff;
            cv0 = b[0];
            cv1 = b[H * W];
        }
    };
    auto cwrite = [&](int q) {
        if (cok) coarse[q][cwidx] = (f32x2){cv0, cv1};
    };

    // ---- fine-halo loop-invariant metadata (2 elems/thread, 484 used) ----
    int  fA[2], fDY[2], fDX[2], fHW[2];
    float fFY[2], fFX[2];
    bool fOK[2], fZF[2];
#pragma unroll
    for (int j = 0; j < 2; ++j) {
        int e = tid + j * 256;
        fOK[j] = (e < 484);
        int hy = e / 22, hx = e - hy * 22;
        int uy = ty0 - 3 + hy, ux = tx0 - 3 + hx;
        fZF[j] = ((unsigned)uy >= 256u) || ((unsigned)ux >= 256u);
        float syf = (float)uy * cs;
        float sxf = (float)ux * cs;
        int y0 = (int)floorf(syf);
        int x0 = (int)floorf(sxf);
        fFY[j] = syf - (float)y0;
        fFX[j] = sxf - (float)x0;
        int y0c = min(max(y0, 0), 127), x0c = min(max(x0, 0), 127);
        int y1c = min(y0c + 1, 127),    x1c = min(x0c + 1, 127);
        int ly  = min(max(y0c - cy0, 0), 13), lx  = min(max(x0c - cx0, 0), 13);
        int ly1 = min(max(y1c - cy0, 0), 13), lx1 = min(max(x1c - cx0, 0), 13);
        fA[j]  = ly * 15 + lx;
        fDY[j] = (ly1 - ly) * 15;
        fDX[j] = lx1 - lx;
        fHW[j] = hy * HSX + hx;
    }

    auto fine_build = [&](int q) {
#pragma unroll
        for (int j = 0; j < 2; ++j) {
            if (fOK[j]) {
                const f32x2* cb = &coarse[q][0];
                f32x2 c00 = cb[fA[j]];
                f32x2 c01 = cb[fA[j] + fDX[j]];
                f32x2 c10 = cb[fA[j] + fDY[j]];
                f32x2 c11 = cb[fA[j] + fDY[j] + fDX[j]];
                f32x2 fyv = (f32x2){fFY[j], fFY[j]};
                f32x2 fxv = (f32x2){fFX[j], fFX[j]};
                f32x2 t0 = c00 + fyv * (c10 - c00);
                f32x2 t1 = c01 + fyv * (c11 - c01);
                f32x2 v  = t0 + fxv * (t1 - t0);
                if (fZF[j]) v = (f32x2){0.f, 0.f};
                halo[q][fHW[j]] = v;
            }
        }
    };

    auto zphase = [&](int q) {
        const f32x2* hb = &halo[q][hbase - 72];   // pre-offset: imm offsets >= 0
        f32x2 z[9];
#pragma unroll
        for (int k = 0; k < 9; ++k) z[k] = (f32x2){0.f, 0.f};
#pragma unroll
        for (int t = 0; t < NT; ++t) {
            f32x2 h = hb[72 + TT.off[t]];
#pragma unroll
            for (int k = 0; k < 9; ++k)
                if (TT.nz[t][k]) z[k] += h * TT.val[t][k];   // v_pk_fma_f32
        }
        unsigned short* zr = &zbuf[tid][0];
        *(uint4*)zr = make_uint4(pkrtz(z[0].x, z[1].x), pkrtz(z[2].x, z[3].x),
                                 pkrtz(z[4].x, z[5].x), pkrtz(z[6].x, z[7].x));
        zr[8] = (unsigned short)(__float_as_uint(z[8].x) >> 16);
        *(uint4*)(zr + 16) = make_uint4(pkrtz(z[0].y, z[1].y), pkrtz(z[2].y, z[3].y),
                                        pkrtz(z[4].y, z[5].y), pkrtz(z[6].y, z[7].y));
        zr[24] = (unsigned short)(__float_as_uint(z[8].y) >> 16);
    };

    f32x4 acc[4][4];
#pragma unroll
    for (int m = 0; m < 4; ++m)
#pragma unroll
        for (int t = 0; t < 4; ++t) acc[m][t] = (f32x4){0.f, 0.f, 0.f, 0.f};

    // ---- prologue ----
    cload(0);
    cwrite(0);
    __syncthreads();
    fine_build(0);
    cload(1);
    __syncthreads();

#pragma unroll 1
    for (int g = 0; g < 32; ++g) {
        const int p = g & 1;
        zphase(p);                       // halo[p] -> zbuf
        if (g < 31) cwrite(p ^ 1);       // regs(g+1) -> coarse[p^1]
        // A-fragments from global (L2-hot), issued before the barrier
        bf16x8 af[4];
        {
            const unsigned short* wp = wsW + g * 2048 + a16 * 32 + kseg;
#pragma unroll
            for (int m = 0; m < 4; ++m)
                af[m] = *(const bf16x8*)(wp + m * 512);
        }
        __syncthreads();                 // B1: zbuf + coarse[p^1] ready

        union { uint2 q2[2]; bf16x8 v; } bfr[4];
#pragma unroll
        for (int t = 0; t < 4; ++t) {
            const unsigned short* zp = &zbuf[wv * 64 + t * 16 + a16][kseg];
            bfr[t].q2[0] = *(const uint2*)zp;
            bfr[t].q2[1] = *(const uint2*)(zp + 4);
        }
#pragma unroll
        for (int m = 0; m < 4; ++m)
#pragma unroll
            for (int t = 0; t < 4; ++t)
                acc[m][t] = __builtin_amdgcn_mfma_f32_16x16x32_bf16(af[m], bfr[t].v, acc[m][t], 0, 0, 0);

        if (g < 31) fine_build(p ^ 1);   // halo[p^1] <- coarse[p^1] (overlaps MFMA)
        if (g < 30) cload(g + 2);        // global -> regs for pair g+2
        __syncthreads();                 // B2
    }

    // ---- epilogue: instance-norm partials + store y ----
#pragma unroll
    for (int m = 0; m < 4; ++m) {
#pragma unroll
        for (int r4 = 0; r4 < 4; ++r4) {
            float s = 0.f, q = 0.f;
#pragma unroll
            for (int t = 0; t < 4; ++t) {
                float v = acc[m][t][r4];
                s += v; q = fmaf(v, v, q);
            }
#pragma unroll
            for (int msk = 1; msk < 16; msk <<= 1) {
                s += __shfl_xor(s, msk);
                q += __shfl_xor(q, msk);
            }
            if (a16 == 0) {
                int o = m * 16 + (l >> 4) * 4 + r4;
                red1[wv][o] = s;
                red2[wv][o] = q;
            }
        }
    }

    const size_t nbase = (size_t)n * COUT * (H2 * W2);
#pragma unroll
    for (int m = 0; m < 4; ++m)
#pragma unroll
        for (int t = 0; t < 4; ++t) {
            int Y = ty0 + wv * 4 + t;
            int X = tx0 + a16;
#pragma unroll
            for (int r4 = 0; r4 < 4; ++r4) {
                int o = m * 16 + (l >> 4) * 4 + r4;
                out[nbase + (size_t)o * (H2 * W2) + Y * W2 + X] = acc[m][t][r4];
            }
        }
    __syncthreads();
    if (tid < 64) {
        float S1 = red1[0][tid] + red1[1][tid] + red1[2][tid] + red1[3][tid];
        float S2 = red2[0][tid] + red2[1][tid] + red2[2][tid] + red2[3][tid];
        ws[WS_P1 + (n * COUT + tid) * 256 + tile] = S1;
        ws[WS_P2 + (n * COUT + tid) * 256 + tile] = S2;
    }
}

// ---------------------------------------------------------------------------
// Stats: reduce 256 tile-partials per (n,c)
// ---------------------------------------------------------------------------
__global__ void stats_kernel(float* __restrict__ ws) {
    const int co  = blockIdx.x;
    const int tid = threadIdx.x;   // 256
    float s1 = ws[WS_P1 + co * 256 + tid];
    float s2 = ws[WS_P2 + co * 256 + tid];
#pragma unroll
    for (int m = 1; m < 64; m <<= 1) { s1 += __shfl_xor(s1, m); s2 += __shfl_xor(s2, m); }
    __shared__ float r1[4], r2[4];
    if ((tid & 63) == 0) { r1[tid >> 6] = s1; r2[tid >> 6] = s2; }
    __syncthreads();
    if (tid == 0) {
        float S1 = r1[0] + r1[1] + r1[2] + r1[3];
        float S2 = r2[0] + r2[1] + r2[2] + r2[3];
        const float inv = 1.f / 65536.f;
        float mu  = S1 * inv;
        float var = S2 * inv - mu * mu;
        ws[WS_MU + co]   = mu;
        ws[WS_RSTD + co] = 1.f / sqrtf(var + 1e-5f);
    }
}

// ---------------------------------------------------------------------------
// Normalize + LeakyReLU(0.2), in place on d_out
// ---------------------------------------------------------------------------
__global__ void norm_kernel(float* __restrict__ out, const float* __restrict__ ws) {
    const int total = NB * COUT * H2 * W2 / 4;
    for (int idx = blockIdx.x * blockDim.x + threadIdx.x; idx < total;
         idx += gridDim.x * blockDim.x) {
        int co = idx >> 14;
        float mu = ws[WS_MU + co];
        float rs = ws[WS_RSTD + co];
        float4 v = ((float4*)out)[idx];
        float* p = (float*)&v;
#pragma unroll
        for (int j = 0; j < 4; ++j) {
            float t = (p[j] - mu) * rs;
            p[j] = (t >= 0.f) ? t : 0.2f * t;
        }
        ((float4*)out)[idx] = v;
    }
}

extern "C" void kernel_launch(void* const* d_in, const int* in_sizes, int n_in,
                              void* d_out, int out_size, void* d_ws, size_t ws_size,
                              hipStream_t stream) {
    const float* img = (const float*)d_in[0];
    const float* wgt = (const float*)d_in[1];
    float* out = (float*)d_out;
    float* ws  = (float*)d_ws;

    setup_w<<<32, 256, 0, stream>>>(wgt, ws);
    conv_kernel<<<NB * 256, 256, 0, stream>>>(img, out, ws);
    stats_kernel<<<256, 256, 0, stream>>>(ws);
    norm_kernel<<<2048, 256, 0, stream>>>(out, ws);
}